// Round 8
// baseline (152.540 us; speedup 1.0000x reference)
//
#include <hip/hip_runtime.h>

typedef _Float16 half8_t __attribute__((ext_vector_type(8)));
typedef _Float16 half4_t __attribute__((ext_vector_type(4)));
typedef _Float16 half2_t __attribute__((ext_vector_type(2)));
typedef __fp16 fp16x2 __attribute__((ext_vector_type(2)));  // cvt_pkrtz return type
typedef float f32x4 __attribute__((ext_vector_type(4)));

static constexpr int SEQ = 2048;
static constexpr int DEMB = 1024;

// SESSION RULES:
//  (r5) no min-waves __launch_bounds__ hints — flipped a passing build to absmax 1.15.
//  (r6) hand-synchronized LDS staging (ds_write -> asm lgkmcnt -> ds_read) is the
//       prime suspect for schedule-sensitive corruption; all cross-lane data
//       movement must be pure-dataflow intrinsics (bpermute/shfl) from now on.

__device__ __forceinline__ float fexp2(float x) {
#if __has_builtin(__builtin_amdgcn_exp2f)
  return __builtin_amdgcn_exp2f(x);
#else
  return exp2f(x);
#endif
}

__device__ __forceinline__ half8_t cvt8(float4 a, float4 b) {
  half8_t xf;
  xf[0] = (_Float16)a.x; xf[1] = (_Float16)a.y;
  xf[2] = (_Float16)a.z; xf[3] = (_Float16)a.w;
  xf[4] = (_Float16)b.x; xf[5] = (_Float16)b.y;
  xf[6] = (_Float16)b.z; xf[7] = (_Float16)b.w;
  return xf;
}

// ---------------- kernel 1: W -> Wt fp16 [192][1024] ----------------
__global__ __launch_bounds__(256) void wt_kernel(const float* __restrict__ Wq,
                                                 const float* __restrict__ Wk,
                                                 const float* __restrict__ Wv,
                                                 _Float16* __restrict__ Wt) {
  int i = blockIdx.x * 256 + threadIdx.x;  // [0, 196608)
  int n = i >> 10;
  int k = i & 1023;
  const float* W = (n < 64) ? Wq : ((n < 128) ? Wk : Wv);
  Wt[i] = (_Float16)W[k * 64 + (n & 63)];
}

// ---------------- kernel 2: QKV projection, 6-way n-split ----------------
// Block = 384 threads = 6 waves sharing 16 x-rows. Wave wv6: role = wv6>>1
// (0=Q,1=K,2=V), nh = wv6&1 (feature half). Each wave: 2 n-tiles, 32-iter
// K-loop, x prefetched 4 deep, W 2 deep (r3-passing structure, just finer
// n-split -> 24 waves/CU instead of 12). No K-split, no LDS, no hints.
__global__ __launch_bounds__(384) void proj_kernel(const float* __restrict__ x,
                                                   const _Float16* __restrict__ Wt,
                                                   _Float16* __restrict__ Qh,
                                                   _Float16* __restrict__ Kh,
                                                   _Float16* __restrict__ Vt) {
  const int lane = threadIdx.x & 63;
  const int wv6 = threadIdx.x >> 6;   // 0..5
  const int role = wv6 >> 1;          // 0=Q, 1=K, 2=V
  const int nh = wv6 & 1;             // feature half within 64
  const int g = lane >> 4;            // 0..3
  const int c = lane & 15;            // 0..15
  const int m0 = blockIdx.x * 16;

  const f32x4 zero = {0.f, 0.f, 0.f, 0.f};
  f32x4 acc[2];
  acc[0] = zero; acc[1] = zero;

  const float* xrow = x + (size_t)(m0 + c) * DEMB + 8 * g;
  const _Float16* Wbase = Wt + (size_t)(role * 64 + nh * 32 + c) * 1024 + 8 * g;
  const bool isV = (role == 2);

  float4 xa[4], xb[4];
  half8_t wf[2][2];
#pragma unroll
  for (int s = 0; s < 4; ++s) {
    xa[s] = *(const float4*)(xrow + 32 * s);
    xb[s] = *(const float4*)(xrow + 32 * s + 4);
  }
#pragma unroll
  for (int s = 0; s < 2; ++s)
#pragma unroll
    for (int j = 0; j < 2; ++j)
      wf[s][j] = *(const half8_t*)(Wbase + j * 16 * 1024 + 32 * s);

#pragma unroll
  for (int it = 0; it < 32; ++it) {
    const int s = it & 3;
    const int ws = it & 1;
    half8_t xf = cvt8(xa[s], xb[s]);
    if (it < 28) {  // prefetch x for it+4
      xa[s] = *(const float4*)(xrow + 32 * it + 128);
      xb[s] = *(const float4*)(xrow + 32 * it + 132);
    }
#pragma unroll
    for (int j = 0; j < 2; ++j) {
      if (!isV)
        acc[j] = __builtin_amdgcn_mfma_f32_16x16x32_f16(wf[ws][j], xf, acc[j], 0, 0, 0);
      else
        acc[j] = __builtin_amdgcn_mfma_f32_16x16x32_f16(xf, wf[ws][j], acc[j], 0, 0, 0);
    }
    if (it < 30) {  // prefetch W for it+2
#pragma unroll
      for (int j = 0; j < 2; ++j)
        wf[ws][j] = *(const half8_t*)(Wbase + j * 16 * 1024 + 32 * (it + 2));
    }
  }

  const int mrow = m0 + c;
  if (role == 0) {
#pragma unroll
    for (int j = 0; j < 2; ++j) {  // Q[m0+c][nh*32 + j*16 + 4g + r]
      half4_t h;
      h[0] = (_Float16)acc[j][0]; h[1] = (_Float16)acc[j][1];
      h[2] = (_Float16)acc[j][2]; h[3] = (_Float16)acc[j][3];
      *(half4_t*)(Qh + mrow * 64 + nh * 32 + j * 16 + 4 * g) = h;
    }
  } else if (role == 1) {
#pragma unroll
    for (int j = 0; j < 2; ++j) {
      half4_t h;
      h[0] = (_Float16)acc[j][0]; h[1] = (_Float16)acc[j][1];
      h[2] = (_Float16)acc[j][2]; h[3] = (_Float16)acc[j][3];
      *(half4_t*)(Kh + mrow * 64 + nh * 32 + j * 16 + 4 * g) = h;
    }
  } else {
    const int b = m0 >> 11;
    const int sbase = (m0 & 2047) + 4 * g;
#pragma unroll
    for (int j = 0; j < 2; ++j) {  // V: D[s=4g+r][h=c] -> Vt[b][h][s]
      int hh = nh * 32 + j * 16 + c;
      half4_t h;
      h[0] = (_Float16)acc[j][0]; h[1] = (_Float16)acc[j][1];
      h[2] = (_Float16)acc[j][2]; h[3] = (_Float16)acc[j][3];
      *(half4_t*)(Vt + (b * 64 + hh) * 2048 + sbase) = h;
    }
  }
}

// ---------------- kernel 3: causal flash attention, 8-way k-split ----------------
// Block = 512 threads = 8 waves, one (b, q-tile of 16 rows). Wave wv handles
// k-blocks jb = wv, wv+8, ...; LDS combine of the 8 partial flash states at end.
// P relayout for PV is a pure in-register ds_bpermute exchange:
//   pv[kt*4+r]@(g,c) = P[q0+c][k0 + kt*16 + 4g + r]
//   target half2 (h,u)@(g,c) = P[q0+c][k0 + 32h + 8g + 2u (+1)]
//     holder lane g_h = 2*(g&1) + (u>>1); packed reg h2[4h + 2*(g>>1) + (u&1)]
// -> 8 cvt_pkrtz + 16 ds_bpermute + 8 selects per k-block. No LDS staging,
// no inline asm, no manual waitcnt.
__global__ __launch_bounds__(512) void attn_kernel(const _Float16* __restrict__ Qh,
                                                   const _Float16* __restrict__ Kh,
                                                   const _Float16* __restrict__ Vt,
                                                   float* __restrict__ out) {
  // Om[8][16][68] floats (34816 B) + Mm (512 B) + Ll (512 B) = 35840 B
  __shared__ __align__(16) char shraw[35840];
  float* Mm = (float*)(shraw + 34816);
  float* Ll = (float*)(shraw + 35328);

  const int tid = threadIdx.x;
  const int lane = tid & 63;
  const int wv = tid >> 6;       // 0..7
  const int g = lane >> 4;
  const int c = lane & 15;
  const int ii = blockIdx.x & 127;
  const int b = blockIdx.x >> 7;
  // interleave big/small q-tiles across consecutive blocks for tail balance
  const int qt = (ii & 1) ? (127 - (ii >> 1)) : (ii >> 1);
  const int q0 = qt * 16;

  const _Float16* Qrow = Qh + (size_t)(b * 2048 + q0 + c) * 64;
  half8_t qf0 = *(const half8_t*)(Qrow + 8 * g);
  half8_t qf1 = *(const half8_t*)(Qrow + 32 + 8 * g);

  const _Float16* Kb = Kh + (size_t)b * 2048 * 64;
  const _Float16* Vb = Vt + (size_t)b * 64 * 2048;

  const f32x4 zero = {0.f, 0.f, 0.f, 0.f};
  f32x4 acc[4];
#pragma unroll
  for (int t = 0; t < 4; ++t) acc[t] = zero;
  float m2 = -3.0e38f, lsum = 0.f;
  const float CS = 0.18033688011112042f;  // 0.125 * log2(e)
  const int q_lane = q0 + c;
  const int nb = ((q0 + 15) >> 6) + 1;

  // bpermute byte-addresses of the two holder lanes (u<2 and u>=2), per lane
  const int addr_u01 = (2 * (g & 1)) * 64 + c * 4;        // g_h = 2*(g&1)
  const int addr_u23 = (2 * (g & 1) + 1) * 64 + c * 4;    // g_h = 2*(g&1)+1
  const bool glo = (g < 2);

  for (int jb = wv; jb < nb; jb += 8) {
    const int k0 = jb * 64;
    // ---- QK^T: S^T = K * Q^T over h=64 (2 chunks of 32) ----
    f32x4 sacc[4];
#pragma unroll
    for (int kt = 0; kt < 4; ++kt) {
      const _Float16* Krow = Kb + (size_t)(k0 + kt * 16 + c) * 64;
      half8_t kf0 = *(const half8_t*)(Krow + 8 * g);
      half8_t kf1 = *(const half8_t*)(Krow + 32 + 8 * g);
      f32x4 t = zero;
      t = __builtin_amdgcn_mfma_f32_16x16x32_f16(kf0, qf0, t, 0, 0, 0);
      t = __builtin_amdgcn_mfma_f32_16x16x32_f16(kf1, qf1, t, 0, 0, 0);
      sacc[kt] = t;
    }
    // ---- hoist V fragment loads so L2 latency overlaps softmax VALU ----
    half8_t vf0[4], vf1[4];
#pragma unroll
    for (int ht = 0; ht < 4; ++ht) {
      const _Float16* Vrow = Vb + (size_t)(16 * ht + c) * 2048 + k0;
      vf0[ht] = *(const half8_t*)(Vrow + 8 * g);
      vf1[ht] = *(const half8_t*)(Vrow + 32 + 8 * g);
    }
    // ---- online softmax (base-2 logits) ----
    const bool full = (k0 + 63 <= q0);
    float pv[16];
    float bmax = -3.0e38f;
#pragma unroll
    for (int kt = 0; kt < 4; ++kt) {
#pragma unroll
      for (int r = 0; r < 4; ++r) {
        float sv = sacc[kt][r] * CS;
        if (!full) {
          int kidx = k0 + kt * 16 + 4 * g + r;
          sv = (kidx > q_lane) ? -3.0e38f : sv;
        }
        pv[kt * 4 + r] = sv;
        bmax = fmaxf(bmax, sv);
      }
    }
    bmax = fmaxf(bmax, __shfl_xor(bmax, 16));
    bmax = fmaxf(bmax, __shfl_xor(bmax, 32));
    const float mnew = fmaxf(m2, bmax);
    const float fsc = fexp2(m2 - mnew);
    m2 = mnew;
    float psum = 0.f;
#pragma unroll
    for (int t = 0; t < 16; ++t) {
      pv[t] = fexp2(pv[t] - m2);
      psum += pv[t];
    }
    lsum = lsum * fsc + psum;
#pragma unroll
    for (int ht = 0; ht < 4; ++ht) {
#pragma unroll
      for (int r = 0; r < 4; ++r) acc[ht][r] *= fsc;
    }
    // ---- pack P to half2 in source-register layout ----
    // h2[kt*2+bb] = (fp16)(pv[kt*4+2bb], pv[kt*4+2bb+1])
    int h2[8];
#pragma unroll
    for (int kt = 0; kt < 4; ++kt) {
#pragma unroll
      for (int bb = 0; bb < 2; ++bb) {
        fp16x2 hv = __builtin_amdgcn_cvt_pkrtz(pv[kt * 4 + 2 * bb],
                                               pv[kt * 4 + 2 * bb + 1]);
        h2[kt * 2 + bb] = __builtin_bit_cast(int, hv);
      }
    }
    // ---- cross-lane exchange to MFMA B-fragment layout ----
    half8_t pf0, pf1;
#pragma unroll
    for (int u = 0; u < 4; ++u) {
      const int addr = (u < 2) ? addr_u01 : addr_u23;
#pragma unroll
      for (int h = 0; h < 2; ++h) {
        int r1 = __builtin_amdgcn_ds_bpermute(addr, h2[4 * h + (u & 1)]);
        int r2 = __builtin_amdgcn_ds_bpermute(addr, h2[4 * h + 2 + (u & 1)]);
        half2_t t = __builtin_bit_cast(half2_t, glo ? r1 : r2);
        if (h == 0) { pf0[2 * u] = t[0]; pf0[2 * u + 1] = t[1]; }
        else        { pf1[2 * u] = t[0]; pf1[2 * u + 1] = t[1]; }
      }
    }
    // ---- PV: O^T += V^T * P^T ----
#pragma unroll
    for (int ht = 0; ht < 4; ++ht) {
      acc[ht] = __builtin_amdgcn_mfma_f32_16x16x32_f16(vf0[ht], pf0, acc[ht], 0, 0, 0);
      acc[ht] = __builtin_amdgcn_mfma_f32_16x16x32_f16(vf1[ht], pf1, acc[ht], 0, 0, 0);
    }
  }
  // ---- reduce l across g within wave, publish partial state ----
  lsum += __shfl_xor(lsum, 16);
  lsum += __shfl_xor(lsum, 32);
  Mm[wv * 16 + c] = m2;   // all g lanes write identical value
  Ll[wv * 16 + c] = lsum;
  float* OmW = (float*)shraw + wv * 1088 + c * 68;
#pragma unroll
  for (int ht = 0; ht < 4; ++ht) {
    *(f32x4*)(OmW + ht * 16 + 4 * g) = acc[ht];
  }
  __syncthreads();
  // ---- combine 8 partials: thread owns (row r, cols 2cp..2cp+1) ----
  const int r = tid & 15;
  const int cp = tid >> 4;  // 0..31
  const float* OmF = (const float*)shraw;
  float mf = Mm[r];
#pragma unroll
  for (int i = 1; i < 8; ++i) mf = fmaxf(mf, Mm[i * 16 + r]);
  float lf = 0.f, o0 = 0.f, o1 = 0.f;
#pragma unroll
  for (int i = 0; i < 8; ++i) {
    float sc = fexp2(Mm[i * 16 + r] - mf);
    lf += Ll[i * 16 + r] * sc;
    const float* p = OmF + i * 1088 + r * 68 + 2 * cp;
    o0 += p[0] * sc;
    o1 += p[1] * sc;
  }
  const float inv = 1.0f / lf;
  float2 o;
  o.x = o0 * inv;
  o.y = o1 * inv;
  *(float2*)(out + (size_t)(b * 2048 + q0 + r) * 64 + 2 * cp) = o;
}

extern "C" void kernel_launch(void* const* d_in, const int* in_sizes, int n_in,
                              void* d_out, int out_size, void* d_ws, size_t ws_size,
                              hipStream_t stream) {
  const float* x  = (const float*)d_in[0];
  const float* Wq = (const float*)d_in[1];
  const float* Wk = (const float*)d_in[2];
  const float* Wv = (const float*)d_in[3];
  char* ws = (char*)d_ws;
  _Float16* Wt = (_Float16*)(ws);                // 192*1024*2      = 393216 B
  _Float16* Qh = (_Float16*)(ws + 393216);       // 16384*64*2      = 2097152 B
  _Float16* Kh = (_Float16*)(ws + 2490368);      // 16384*64*2
  _Float16* Vt = (_Float16*)(ws + 4587520);      // 8*64*2048*2
  float* out = (float*)d_out;

  wt_kernel<<<dim3(768), dim3(256), 0, stream>>>(Wq, Wk, Wv, Wt);
  proj_kernel<<<dim3(1024), dim3(384), 0, stream>>>(x, Wt, Qh, Kh, Vt);
  attn_kernel<<<dim3(1024), dim3(512), 0, stream>>>(Qh, Kh, Vt, out);
}

// Round 9
// 92.605 us; speedup vs baseline: 1.6472x; 1.6472x over previous
//
#include <hip/hip_runtime.h>

typedef _Float16 half8_t __attribute__((ext_vector_type(8)));
typedef _Float16 half4_t __attribute__((ext_vector_type(4)));
typedef _Float16 half2_t __attribute__((ext_vector_type(2)));
typedef __fp16 fp16x2 __attribute__((ext_vector_type(2)));  // cvt_pkrtz return type
typedef float f32x4 __attribute__((ext_vector_type(4)));

static constexpr int SEQ = 2048;
static constexpr int DEMB = 1024;

// SESSION RULES:
//  (r5) no min-waves __launch_bounds__ hints — flipped a passing build to absmax 1.15.
//  (r6) no hand-synchronized LDS staging (ds_write -> asm lgkmcnt -> ds_read in one
//       thread's stream). LDS use only via the standard __syncthreads() pattern;
//       cross-lane data movement via bpermute/shfl intrinsics.
//  (r8) per-wave ILP via source prefetch gets legally re-serialized by the
//       compiler (VGPR squeeze). Hide latency structurally: LDS staging + waves.

__device__ __forceinline__ float fexp2(float x) {
#if __has_builtin(__builtin_amdgcn_exp2f)
  return __builtin_amdgcn_exp2f(x);
#else
  return exp2f(x);
#endif
}

__device__ __forceinline__ half8_t cvt8(float4 a, float4 b) {
  half8_t xf;
  xf[0] = (_Float16)a.x; xf[1] = (_Float16)a.y;
  xf[2] = (_Float16)a.z; xf[3] = (_Float16)a.w;
  xf[4] = (_Float16)b.x; xf[5] = (_Float16)b.y;
  xf[6] = (_Float16)b.z; xf[7] = (_Float16)b.w;
  return xf;
}

// ---------------- kernel 1: W -> Wt fp16 [192][1024] ----------------
__global__ __launch_bounds__(256) void wt_kernel(const float* __restrict__ Wq,
                                                 const float* __restrict__ Wk,
                                                 const float* __restrict__ Wv,
                                                 _Float16* __restrict__ Wt) {
  int i = blockIdx.x * 256 + threadIdx.x;  // [0, 196608)
  int n = i >> 10;
  int k = i & 1023;
  const float* W = (n < 64) ? Wq : ((n < 128) ? Wk : Wv);
  Wt[i] = (_Float16)W[k * 64 + (n & 63)];
}

// ---------------- kernel 2: QKV projection, LDS-staged GEMM ----------------
// Block = 256 threads = 4 waves, M-tile = 32 x-rows, grid 512 (2 blocks/CU).
// K-loop: 32 steps of K=32. Per step the 4 KB x-tile (32x32 f32) is staged to
// LDS ONCE (each thread: 16 B global reg-load issued early, ds_write at iter
// end, __syncthreads) and consumed by all 4 waves -> x read exactly once from
// HBM, load->use decoupled by a full iteration. XOR-swizzle (byte^=(row&7)<<4,
// same involution both sides) makes the stride-128B ds_read_b128 ~conflict-free.
// Wave wv computes n-tiles {3wv+j}: nt 0-7 swapped (Q/K row-major), 8-11 normal
// (V transposed store). W fragments direct from L2, 1-step named prefetch.
__global__ __launch_bounds__(256) void proj_kernel(const float* __restrict__ x,
                                                   const _Float16* __restrict__ Wt,
                                                   _Float16* __restrict__ Qh,
                                                   _Float16* __restrict__ Kh,
                                                   _Float16* __restrict__ Vt) {
  __shared__ __align__(16) char sbuf[8192];  // 2 x 4 KB x-tile (f32, swizzled)

  const int tid = threadIdx.x;
  const int lane = tid & 63;
  const int wv = tid >> 6;        // 0..3
  const int g = lane >> 4;        // 0..3
  const int c = lane & 15;        // 0..15
  const int m0 = blockIdx.x * 32;

  // staging: thread tid owns tile row srow = tid>>3, 16 B at col (tid&7)*16B
  const int srow = tid >> 3;
  const float* xsrc = x + (size_t)(m0 + srow) * DEMB + (tid & 7) * 4;
  char* lws = sbuf + ((unsigned)(tid * 16) ^ (unsigned)((srow & 7) << 4));

  // read addresses: row = ms*16 + c, cols 8g.. (f32); swizzle by (row&7)=(c&7)
  const unsigned sw = (unsigned)((c & 7) << 4);
  const unsigned rA = (unsigned)(c * 128 + g * 32);

  const f32x4 zero = {0.f, 0.f, 0.f, 0.f};
  f32x4 acc[2][3];
#pragma unroll
  for (int ms = 0; ms < 2; ++ms)
#pragma unroll
    for (int j = 0; j < 3; ++j) acc[ms][j] = zero;

  const _Float16* wb0 = Wt + (size_t)((3 * wv + 0) * 16 + c) * 1024 + 8 * g;
  const _Float16* wb1 = Wt + (size_t)((3 * wv + 1) * 16 + c) * 1024 + 8 * g;
  const _Float16* wb2 = Wt + (size_t)((3 * wv + 2) * 16 + c) * 1024 + 8 * g;
  half8_t wf0 = *(const half8_t*)(wb0);
  half8_t wf1 = *(const half8_t*)(wb1);
  half8_t wf2 = *(const half8_t*)(wb2);
  const bool swapped = (3 * wv + 2) < 8 || true;  // per-tile below; placeholder unused

  // prologue: stage k-step 0
  {
    float4 xa = *(const float4*)(xsrc);
    *(float4*)(lws) = xa;
  }
  __syncthreads();

  for (int t = 0; t < 31; ++t) {
    const int kc = (t + 1) * 32;
    // issue next-step loads early (consumed at iter end / next iter)
    float4 xn = *(const float4*)(xsrc + kc);
    half8_t wn0 = *(const half8_t*)(wb0 + kc);
    half8_t wn1 = *(const half8_t*)(wb1 + kc);
    half8_t wn2 = *(const half8_t*)(wb2 + kc);
    // compute step t from buf[t&1]
    const char* rb = sbuf + (t & 1) * 4096;
    half8_t xf[2];
#pragma unroll
    for (int ms = 0; ms < 2; ++ms) {
      const unsigned base = rA + (unsigned)(ms * 2048);
      float4 xlo = *(const float4*)(rb + (base ^ sw));
      float4 xhi = *(const float4*)(rb + ((base + 16) ^ sw));
      xf[ms] = cvt8(xlo, xhi);
    }
#pragma unroll
    for (int j = 0; j < 3; ++j) {
      half8_t wcur = (j == 0) ? wf0 : ((j == 1) ? wf1 : wf2);
      const int nt = 3 * wv + j;
      if (nt < 8) {  // Q/K: swapped -> D[n][m]
        acc[0][j] = __builtin_amdgcn_mfma_f32_16x16x32_f16(wcur, xf[0], acc[0][j], 0, 0, 0);
        acc[1][j] = __builtin_amdgcn_mfma_f32_16x16x32_f16(wcur, xf[1], acc[1][j], 0, 0, 0);
      } else {       // V: normal -> D[m][n]
        acc[0][j] = __builtin_amdgcn_mfma_f32_16x16x32_f16(xf[0], wcur, acc[0][j], 0, 0, 0);
        acc[1][j] = __builtin_amdgcn_mfma_f32_16x16x32_f16(xf[1], wcur, acc[1][j], 0, 0, 0);
      }
    }
    wf0 = wn0; wf1 = wn1; wf2 = wn2;
    // stage step t+1 (compiler waits on xn's vmcnt before the ds_write)
    *(float4*)(lws + ((t + 1) & 1) * 4096) = xn;
    __syncthreads();
  }
  // final compute: t = 31 from buf[1]
  {
    const char* rb = sbuf + 4096;
    half8_t xf[2];
#pragma unroll
    for (int ms = 0; ms < 2; ++ms) {
      const unsigned base = rA + (unsigned)(ms * 2048);
      float4 xlo = *(const float4*)(rb + (base ^ sw));
      float4 xhi = *(const float4*)(rb + ((base + 16) ^ sw));
      xf[ms] = cvt8(xlo, xhi);
    }
#pragma unroll
    for (int j = 0; j < 3; ++j) {
      half8_t wcur = (j == 0) ? wf0 : ((j == 1) ? wf1 : wf2);
      const int nt = 3 * wv + j;
      if (nt < 8) {
        acc[0][j] = __builtin_amdgcn_mfma_f32_16x16x32_f16(wcur, xf[0], acc[0][j], 0, 0, 0);
        acc[1][j] = __builtin_amdgcn_mfma_f32_16x16x32_f16(wcur, xf[1], acc[1][j], 0, 0, 0);
      } else {
        acc[0][j] = __builtin_amdgcn_mfma_f32_16x16x32_f16(xf[0], wcur, acc[0][j], 0, 0, 0);
        acc[1][j] = __builtin_amdgcn_mfma_f32_16x16x32_f16(xf[1], wcur, acc[1][j], 0, 0, 0);
      }
    }
  }

  // ---- stores ----
  const int b = m0 >> 11;
#pragma unroll
  for (int j = 0; j < 3; ++j) {
    const int nt = 3 * wv + j;
#pragma unroll
    for (int ms = 0; ms < 2; ++ms) {
      half4_t h;
      h[0] = (_Float16)acc[ms][j][0]; h[1] = (_Float16)acc[ms][j][1];
      h[2] = (_Float16)acc[ms][j][2]; h[3] = (_Float16)acc[ms][j][3];
      if (nt < 4) {        // Q: D[n][m]: row m0+ms*16+c, col nt*16+4g+r
        *(half4_t*)(Qh + (size_t)(m0 + ms * 16 + c) * 64 + nt * 16 + 4 * g) = h;
      } else if (nt < 8) { // K
        *(half4_t*)(Kh + (size_t)(m0 + ms * 16 + c) * 64 + (nt - 4) * 16 + 4 * g) = h;
      } else {             // V: D[s][h]: h=(nt-8)*16+c, s=m0+ms*16+4g+r -> Vt[b][h][s]
        const int hh = (nt - 8) * 16 + c;
        const int s0 = (m0 & 2047) + ms * 16 + 4 * g;
        *(half4_t*)(Vt + (size_t)(b * 64 + hh) * 2048 + s0) = h;
      }
    }
  }
}

// ---------------- kernel 3: causal flash attention, 8-way k-split ----------------
// (verbatim round-8 passing version)
__global__ __launch_bounds__(512) void attn_kernel(const _Float16* __restrict__ Qh,
                                                   const _Float16* __restrict__ Kh,
                                                   const _Float16* __restrict__ Vt,
                                                   float* __restrict__ out) {
  // Om[8][16][68] floats (34816 B) + Mm (512 B) + Ll (512 B) = 35840 B
  __shared__ __align__(16) char shraw[35840];
  float* Mm = (float*)(shraw + 34816);
  float* Ll = (float*)(shraw + 35328);

  const int tid = threadIdx.x;
  const int lane = tid & 63;
  const int wv = tid >> 6;       // 0..7
  const int g = lane >> 4;
  const int c = lane & 15;
  const int ii = blockIdx.x & 127;
  const int b = blockIdx.x >> 7;
  // interleave big/small q-tiles across consecutive blocks for tail balance
  const int qt = (ii & 1) ? (127 - (ii >> 1)) : (ii >> 1);
  const int q0 = qt * 16;

  const _Float16* Qrow = Qh + (size_t)(b * 2048 + q0 + c) * 64;
  half8_t qf0 = *(const half8_t*)(Qrow + 8 * g);
  half8_t qf1 = *(const half8_t*)(Qrow + 32 + 8 * g);

  const _Float16* Kb = Kh + (size_t)b * 2048 * 64;
  const _Float16* Vb = Vt + (size_t)b * 64 * 2048;

  const f32x4 zero = {0.f, 0.f, 0.f, 0.f};
  f32x4 acc[4];
#pragma unroll
  for (int t = 0; t < 4; ++t) acc[t] = zero;
  float m2 = -3.0e38f, lsum = 0.f;
  const float CS = 0.18033688011112042f;  // 0.125 * log2(e)
  const int q_lane = q0 + c;
  const int nb = ((q0 + 15) >> 6) + 1;

  // bpermute byte-addresses of the two holder lanes (u<2 and u>=2), per lane
  const int addr_u01 = (2 * (g & 1)) * 64 + c * 4;        // g_h = 2*(g&1)
  const int addr_u23 = (2 * (g & 1) + 1) * 64 + c * 4;    // g_h = 2*(g&1)+1
  const bool glo = (g < 2);

  for (int jb = wv; jb < nb; jb += 8) {
    const int k0 = jb * 64;
    // ---- QK^T: S^T = K * Q^T over h=64 (2 chunks of 32) ----
    f32x4 sacc[4];
#pragma unroll
    for (int kt = 0; kt < 4; ++kt) {
      const _Float16* Krow = Kb + (size_t)(k0 + kt * 16 + c) * 64;
      half8_t kf0 = *(const half8_t*)(Krow + 8 * g);
      half8_t kf1 = *(const half8_t*)(Krow + 32 + 8 * g);
      f32x4 t = zero;
      t = __builtin_amdgcn_mfma_f32_16x16x32_f16(kf0, qf0, t, 0, 0, 0);
      t = __builtin_amdgcn_mfma_f32_16x16x32_f16(kf1, qf1, t, 0, 0, 0);
      sacc[kt] = t;
    }
    // ---- hoist V fragment loads so L2 latency overlaps softmax VALU ----
    half8_t vf0[4], vf1[4];
#pragma unroll
    for (int ht = 0; ht < 4; ++ht) {
      const _Float16* Vrow = Vb + (size_t)(16 * ht + c) * 2048 + k0;
      vf0[ht] = *(const half8_t*)(Vrow + 8 * g);
      vf1[ht] = *(const half8_t*)(Vrow + 32 + 8 * g);
    }
    // ---- online softmax (base-2 logits) ----
    const bool full = (k0 + 63 <= q0);
    float pv[16];
    float bmax = -3.0e38f;
#pragma unroll
    for (int kt = 0; kt < 4; ++kt) {
#pragma unroll
      for (int r = 0; r < 4; ++r) {
        float sv = sacc[kt][r] * CS;
        if (!full) {
          int kidx = k0 + kt * 16 + 4 * g + r;
          sv = (kidx > q_lane) ? -3.0e38f : sv;
        }
        pv[kt * 4 + r] = sv;
        bmax = fmaxf(bmax, sv);
      }
    }
    bmax = fmaxf(bmax, __shfl_xor(bmax, 16));
    bmax = fmaxf(bmax, __shfl_xor(bmax, 32));
    const float mnew = fmaxf(m2, bmax);
    const float fsc = fexp2(m2 - mnew);
    m2 = mnew;
    float psum = 0.f;
#pragma unroll
    for (int t = 0; t < 16; ++t) {
      pv[t] = fexp2(pv[t] - m2);
      psum += pv[t];
    }
    lsum = lsum * fsc + psum;
#pragma unroll
    for (int ht = 0; ht < 4; ++ht) {
#pragma unroll
      for (int r = 0; r < 4; ++r) acc[ht][r] *= fsc;
    }
    // ---- pack P to half2 in source-register layout ----
    int h2[8];
#pragma unroll
    for (int kt = 0; kt < 4; ++kt) {
#pragma unroll
      for (int bb = 0; bb < 2; ++bb) {
        fp16x2 hv = __builtin_amdgcn_cvt_pkrtz(pv[kt * 4 + 2 * bb],
                                               pv[kt * 4 + 2 * bb + 1]);
        h2[kt * 2 + bb] = __builtin_bit_cast(int, hv);
      }
    }
    // ---- cross-lane exchange to MFMA B-fragment layout ----
    half8_t pf0, pf1;
#pragma unroll
    for (int u = 0; u < 4; ++u) {
      const int addr = (u < 2) ? addr_u01 : addr_u23;
#pragma unroll
      for (int h = 0; h < 2; ++h) {
        int r1 = __builtin_amdgcn_ds_bpermute(addr, h2[4 * h + (u & 1)]);
        int r2 = __builtin_amdgcn_ds_bpermute(addr, h2[4 * h + 2 + (u & 1)]);
        half2_t t = __builtin_bit_cast(half2_t, glo ? r1 : r2);
        if (h == 0) { pf0[2 * u] = t[0]; pf0[2 * u + 1] = t[1]; }
        else        { pf1[2 * u] = t[0]; pf1[2 * u + 1] = t[1]; }
      }
    }
    // ---- PV: O^T += V^T * P^T ----
#pragma unroll
    for (int ht = 0; ht < 4; ++ht) {
      acc[ht] = __builtin_amdgcn_mfma_f32_16x16x32_f16(vf0[ht], pf0, acc[ht], 0, 0, 0);
      acc[ht] = __builtin_amdgcn_mfma_f32_16x16x32_f16(vf1[ht], pf1, acc[ht], 0, 0, 0);
    }
  }
  // ---- reduce l across g within wave, publish partial state ----
  lsum += __shfl_xor(lsum, 16);
  lsum += __shfl_xor(lsum, 32);
  Mm[wv * 16 + c] = m2;   // all g lanes write identical value
  Ll[wv * 16 + c] = lsum;
  float* OmW = (float*)shraw + wv * 1088 + c * 68;
#pragma unroll
  for (int ht = 0; ht < 4; ++ht) {
    *(f32x4*)(OmW + ht * 16 + 4 * g) = acc[ht];
  }
  __syncthreads();
  // ---- combine 8 partials: thread owns (row r, cols 2cp..2cp+1) ----
  const int r = tid & 15;
  const int cp = tid >> 4;  // 0..31
  const float* OmF = (const float*)shraw;
  float mf = Mm[r];
#pragma unroll
  for (int i = 1; i < 8; ++i) mf = fmaxf(mf, Mm[i * 16 + r]);
  float lf = 0.f, o0 = 0.f, o1 = 0.f;
#pragma unroll
  for (int i = 0; i < 8; ++i) {
    float sc = fexp2(Mm[i * 16 + r] - mf);
    lf += Ll[i * 16 + r] * sc;
    const float* p = OmF + i * 1088 + r * 68 + 2 * cp;
    o0 += p[0] * sc;
    o1 += p[1] * sc;
  }
  const float inv = 1.0f / lf;
  float2 o;
  o.x = o0 * inv;
  o.y = o1 * inv;
  *(float2*)(out + (size_t)(b * 2048 + q0 + r) * 64 + 2 * cp) = o;
}

extern "C" void kernel_launch(void* const* d_in, const int* in_sizes, int n_in,
                              void* d_out, int out_size, void* d_ws, size_t ws_size,
                              hipStream_t stream) {
  const float* x  = (const float*)d_in[0];
  const float* Wq = (const float*)d_in[1];
  const float* Wk = (const float*)d_in[2];
  const float* Wv = (const float*)d_in[3];
  char* ws = (char*)d_ws;
  _Float16* Wt = (_Float16*)(ws);                // 192*1024*2      = 393216 B
  _Float16* Qh = (_Float16*)(ws + 393216);       // 16384*64*2      = 2097152 B
  _Float16* Kh = (_Float16*)(ws + 2490368);      // 16384*64*2
  _Float16* Vt = (_Float16*)(ws + 4587520);      // 8*64*2048*2
  float* out = (float*)d_out;

  wt_kernel<<<dim3(768), dim3(256), 0, stream>>>(Wq, Wk, Wv, Wt);
  proj_kernel<<<dim3(512), dim3(256), 0, stream>>>(x, Wt, Qh, Kh, Vt);
  attn_kernel<<<dim3(1024), dim3(512), 0, stream>>>(Qh, Kh, Vt, out);
}

// Round 10
// 70.891 us; speedup vs baseline: 2.1517x; 1.3063x over previous
//
#include <hip/hip_runtime.h>

typedef _Float16 half8_t __attribute__((ext_vector_type(8)));
typedef _Float16 half4_t __attribute__((ext_vector_type(4)));
typedef _Float16 half2_t __attribute__((ext_vector_type(2)));
typedef __fp16 fp16x2 __attribute__((ext_vector_type(2)));  // cvt_pkrtz return type
typedef float f32x4 __attribute__((ext_vector_type(4)));

static constexpr int SEQ = 2048;
static constexpr int DEMB = 1024;

// SESSION RULES:
//  (r5) no min-waves __launch_bounds__ hints — flipped a passing build to absmax 1.15.
//  (r6) no hand-synchronized LDS staging; LDS only via __syncthreads(); cross-lane
//       movement via bpermute/shfl intrinsics.
//  (r8) per-wave ILP via source prefetch gets legally re-serialized by the
//       compiler. Hide latency structurally: LDS staging + waves.
//  (r9) equalize work per BLOCK (complementary q-tile pairs) — block-level work
//       variance (1:32) caused idle-at-barrier waves + drain tail (21% occupancy).

__device__ __forceinline__ float fexp2(float x) {
#if __has_builtin(__builtin_amdgcn_exp2f)
  return __builtin_amdgcn_exp2f(x);
#else
  return exp2f(x);
#endif
}

__device__ __forceinline__ half8_t cvt8(float4 a, float4 b) {
  half8_t xf;
  xf[0] = (_Float16)a.x; xf[1] = (_Float16)a.y;
  xf[2] = (_Float16)a.z; xf[3] = (_Float16)a.w;
  xf[4] = (_Float16)b.x; xf[5] = (_Float16)b.y;
  xf[6] = (_Float16)b.z; xf[7] = (_Float16)b.w;
  return xf;
}

// ---------------- kernel 1: W -> Wt fp16 [192][1024] ----------------
__global__ __launch_bounds__(256) void wt_kernel(const float* __restrict__ Wq,
                                                 const float* __restrict__ Wk,
                                                 const float* __restrict__ Wv,
                                                 _Float16* __restrict__ Wt) {
  int i = blockIdx.x * 256 + threadIdx.x;  // [0, 196608)
  int n = i >> 10;
  int k = i & 1023;
  const float* W = (n < 64) ? Wq : ((n < 128) ? Wk : Wv);
  Wt[i] = (_Float16)W[k * 64 + (n & 63)];
}

// ---------------- kernel 2: QKV projection, LDS-staged GEMM (r9 passing) ----------------
__global__ __launch_bounds__(256) void proj_kernel(const float* __restrict__ x,
                                                   const _Float16* __restrict__ Wt,
                                                   _Float16* __restrict__ Qh,
                                                   _Float16* __restrict__ Kh,
                                                   _Float16* __restrict__ Vt) {
  __shared__ __align__(16) char sbuf[8192];  // 2 x 4 KB x-tile (f32, swizzled)

  const int tid = threadIdx.x;
  const int lane = tid & 63;
  const int wv = tid >> 6;        // 0..3
  const int g = lane >> 4;        // 0..3
  const int c = lane & 15;        // 0..15
  const int m0 = blockIdx.x * 32;

  const int srow = tid >> 3;
  const float* xsrc = x + (size_t)(m0 + srow) * DEMB + (tid & 7) * 4;
  char* lws = sbuf + ((unsigned)(tid * 16) ^ (unsigned)((srow & 7) << 4));

  const unsigned sw = (unsigned)((c & 7) << 4);
  const unsigned rA = (unsigned)(c * 128 + g * 32);

  const f32x4 zero = {0.f, 0.f, 0.f, 0.f};
  f32x4 acc[2][3];
#pragma unroll
  for (int ms = 0; ms < 2; ++ms)
#pragma unroll
    for (int j = 0; j < 3; ++j) acc[ms][j] = zero;

  const _Float16* wb0 = Wt + (size_t)((3 * wv + 0) * 16 + c) * 1024 + 8 * g;
  const _Float16* wb1 = Wt + (size_t)((3 * wv + 1) * 16 + c) * 1024 + 8 * g;
  const _Float16* wb2 = Wt + (size_t)((3 * wv + 2) * 16 + c) * 1024 + 8 * g;
  half8_t wf0 = *(const half8_t*)(wb0);
  half8_t wf1 = *(const half8_t*)(wb1);
  half8_t wf2 = *(const half8_t*)(wb2);

  // prologue: stage k-step 0
  {
    float4 xa = *(const float4*)(xsrc);
    *(float4*)(lws) = xa;
  }
  __syncthreads();

  for (int t = 0; t < 31; ++t) {
    const int kc = (t + 1) * 32;
    float4 xn = *(const float4*)(xsrc + kc);
    half8_t wn0 = *(const half8_t*)(wb0 + kc);
    half8_t wn1 = *(const half8_t*)(wb1 + kc);
    half8_t wn2 = *(const half8_t*)(wb2 + kc);
    const char* rb = sbuf + (t & 1) * 4096;
    half8_t xf[2];
#pragma unroll
    for (int ms = 0; ms < 2; ++ms) {
      const unsigned base = rA + (unsigned)(ms * 2048);
      float4 xlo = *(const float4*)(rb + (base ^ sw));
      float4 xhi = *(const float4*)(rb + ((base + 16) ^ sw));
      xf[ms] = cvt8(xlo, xhi);
    }
#pragma unroll
    for (int j = 0; j < 3; ++j) {
      half8_t wcur = (j == 0) ? wf0 : ((j == 1) ? wf1 : wf2);
      const int nt = 3 * wv + j;
      if (nt < 8) {
        acc[0][j] = __builtin_amdgcn_mfma_f32_16x16x32_f16(wcur, xf[0], acc[0][j], 0, 0, 0);
        acc[1][j] = __builtin_amdgcn_mfma_f32_16x16x32_f16(wcur, xf[1], acc[1][j], 0, 0, 0);
      } else {
        acc[0][j] = __builtin_amdgcn_mfma_f32_16x16x32_f16(xf[0], wcur, acc[0][j], 0, 0, 0);
        acc[1][j] = __builtin_amdgcn_mfma_f32_16x16x32_f16(xf[1], wcur, acc[1][j], 0, 0, 0);
      }
    }
    wf0 = wn0; wf1 = wn1; wf2 = wn2;
    *(float4*)(lws + ((t + 1) & 1) * 4096) = xn;
    __syncthreads();
  }
  {
    const char* rb = sbuf + 4096;
    half8_t xf[2];
#pragma unroll
    for (int ms = 0; ms < 2; ++ms) {
      const unsigned base = rA + (unsigned)(ms * 2048);
      float4 xlo = *(const float4*)(rb + (base ^ sw));
      float4 xhi = *(const float4*)(rb + ((base + 16) ^ sw));
      xf[ms] = cvt8(xlo, xhi);
    }
#pragma unroll
    for (int j = 0; j < 3; ++j) {
      half8_t wcur = (j == 0) ? wf0 : ((j == 1) ? wf1 : wf2);
      const int nt = 3 * wv + j;
      if (nt < 8) {
        acc[0][j] = __builtin_amdgcn_mfma_f32_16x16x32_f16(wcur, xf[0], acc[0][j], 0, 0, 0);
        acc[1][j] = __builtin_amdgcn_mfma_f32_16x16x32_f16(wcur, xf[1], acc[1][j], 0, 0, 0);
      } else {
        acc[0][j] = __builtin_amdgcn_mfma_f32_16x16x32_f16(xf[0], wcur, acc[0][j], 0, 0, 0);
        acc[1][j] = __builtin_amdgcn_mfma_f32_16x16x32_f16(xf[1], wcur, acc[1][j], 0, 0, 0);
      }
    }
  }

  const int b = m0 >> 11;
#pragma unroll
  for (int j = 0; j < 3; ++j) {
    const int nt = 3 * wv + j;
#pragma unroll
    for (int ms = 0; ms < 2; ++ms) {
      half4_t h;
      h[0] = (_Float16)acc[ms][j][0]; h[1] = (_Float16)acc[ms][j][1];
      h[2] = (_Float16)acc[ms][j][2]; h[3] = (_Float16)acc[ms][j][3];
      if (nt < 4) {
        *(half4_t*)(Qh + (size_t)(m0 + ms * 16 + c) * 64 + nt * 16 + 4 * g) = h;
      } else if (nt < 8) {
        *(half4_t*)(Kh + (size_t)(m0 + ms * 16 + c) * 64 + (nt - 4) * 16 + 4 * g) = h;
      } else {
        const int hh = (nt - 8) * 16 + c;
        const int s0 = (m0 & 2047) + ms * 16 + 4 * g;
        *(half4_t*)(Vt + (size_t)(b * 64 + hh) * 2048 + s0) = h;
      }
    }
  }
}

// ---------------- attn helpers ----------------
// Flash loop for one q-tile (16 rows at q0), wave-private state, k-split 8.
__device__ __forceinline__ void flash_tile(int q0, int wv, int g, int c,
                                           const _Float16* __restrict__ Qb,
                                           const _Float16* __restrict__ Kb,
                                           const _Float16* __restrict__ Vb,
                                           f32x4 (&acc)[4], float& m2, float& lsum) {
  const f32x4 zero = {0.f, 0.f, 0.f, 0.f};
  const float CS = 0.18033688011112042f;  // 0.125 * log2(e)
  const int q_lane = q0 + c;
  const int nb = ((q0 + 15) >> 6) + 1;

  const _Float16* Qrow = Qb + (size_t)(q0 + c) * 64;
  half8_t qf0 = *(const half8_t*)(Qrow + 8 * g);
  half8_t qf1 = *(const half8_t*)(Qrow + 32 + 8 * g);

  const int addr_u01 = (2 * (g & 1)) * 64 + c * 4;
  const int addr_u23 = (2 * (g & 1) + 1) * 64 + c * 4;
  const bool glo = (g < 2);

  for (int jb = wv; jb < nb; jb += 8) {
    const int k0 = jb * 64;
    f32x4 sacc[4];
#pragma unroll
    for (int kt = 0; kt < 4; ++kt) {
      const _Float16* Krow = Kb + (size_t)(k0 + kt * 16 + c) * 64;
      half8_t kf0 = *(const half8_t*)(Krow + 8 * g);
      half8_t kf1 = *(const half8_t*)(Krow + 32 + 8 * g);
      f32x4 t = zero;
      t = __builtin_amdgcn_mfma_f32_16x16x32_f16(kf0, qf0, t, 0, 0, 0);
      t = __builtin_amdgcn_mfma_f32_16x16x32_f16(kf1, qf1, t, 0, 0, 0);
      sacc[kt] = t;
    }
    half8_t vf0[4], vf1[4];
#pragma unroll
    for (int ht = 0; ht < 4; ++ht) {
      const _Float16* Vrow = Vb + (size_t)(16 * ht + c) * 2048 + k0;
      vf0[ht] = *(const half8_t*)(Vrow + 8 * g);
      vf1[ht] = *(const half8_t*)(Vrow + 32 + 8 * g);
    }
    const bool full = (k0 + 63 <= q0);
    float pv[16];
    float bmax = -3.0e38f;
#pragma unroll
    for (int kt = 0; kt < 4; ++kt) {
#pragma unroll
      for (int r = 0; r < 4; ++r) {
        float sv = sacc[kt][r] * CS;
        if (!full) {
          int kidx = k0 + kt * 16 + 4 * g + r;
          sv = (kidx > q_lane) ? -3.0e38f : sv;
        }
        pv[kt * 4 + r] = sv;
        bmax = fmaxf(bmax, sv);
      }
    }
    bmax = fmaxf(bmax, __shfl_xor(bmax, 16));
    bmax = fmaxf(bmax, __shfl_xor(bmax, 32));
    const float mnew = fmaxf(m2, bmax);
    const float fsc = fexp2(m2 - mnew);
    m2 = mnew;
    float psum = 0.f;
#pragma unroll
    for (int t = 0; t < 16; ++t) {
      pv[t] = fexp2(pv[t] - m2);
      psum += pv[t];
    }
    lsum = lsum * fsc + psum;
#pragma unroll
    for (int ht = 0; ht < 4; ++ht) {
#pragma unroll
      for (int r = 0; r < 4; ++r) acc[ht][r] *= fsc;
    }
    int h2[8];
#pragma unroll
    for (int kt = 0; kt < 4; ++kt) {
#pragma unroll
      for (int bb = 0; bb < 2; ++bb) {
        fp16x2 hv = __builtin_amdgcn_cvt_pkrtz(pv[kt * 4 + 2 * bb],
                                               pv[kt * 4 + 2 * bb + 1]);
        h2[kt * 2 + bb] = __builtin_bit_cast(int, hv);
      }
    }
    half8_t pf0, pf1;
#pragma unroll
    for (int u = 0; u < 4; ++u) {
      const int addr = (u < 2) ? addr_u01 : addr_u23;
#pragma unroll
      for (int h = 0; h < 2; ++h) {
        int r1 = __builtin_amdgcn_ds_bpermute(addr, h2[4 * h + (u & 1)]);
        int r2 = __builtin_amdgcn_ds_bpermute(addr, h2[4 * h + 2 + (u & 1)]);
        half2_t t = __builtin_bit_cast(half2_t, glo ? r1 : r2);
        if (h == 0) { pf0[2 * u] = t[0]; pf0[2 * u + 1] = t[1]; }
        else        { pf1[2 * u] = t[0]; pf1[2 * u + 1] = t[1]; }
      }
    }
#pragma unroll
    for (int ht = 0; ht < 4; ++ht) {
      acc[ht] = __builtin_amdgcn_mfma_f32_16x16x32_f16(vf0[ht], pf0, acc[ht], 0, 0, 0);
      acc[ht] = __builtin_amdgcn_mfma_f32_16x16x32_f16(vf1[ht], pf1, acc[ht], 0, 0, 0);
    }
  }
}

// Combine 8 wave partials of one q-tile via LDS; all threads execute all
// barriers uniformly. shraw layout: Om[8][16][68] f32 | Mm[128] | Ll[128].
__device__ __forceinline__ void combine_tile(char* shraw, int tid, int wv, int g, int c,
                                             int b, int q0, f32x4 (&acc)[4],
                                             float m2, float lsum,
                                             float* __restrict__ out) {
  float* Mm = (float*)(shraw + 34816);
  float* Ll = (float*)(shraw + 35328);
  lsum += __shfl_xor(lsum, 16);
  lsum += __shfl_xor(lsum, 32);
  Mm[wv * 16 + c] = m2;
  Ll[wv * 16 + c] = lsum;
  float* OmW = (float*)shraw + wv * 1088 + c * 68;
#pragma unroll
  for (int ht = 0; ht < 4; ++ht) {
    *(f32x4*)(OmW + ht * 16 + 4 * g) = acc[ht];
  }
  __syncthreads();
  const int r = tid & 15;
  const int cp = tid >> 4;  // 0..31
  const float* OmF = (const float*)shraw;
  float mf = Mm[r];
#pragma unroll
  for (int i = 1; i < 8; ++i) mf = fmaxf(mf, Mm[i * 16 + r]);
  float lf = 0.f, o0 = 0.f, o1 = 0.f;
#pragma unroll
  for (int i = 0; i < 8; ++i) {
    float sc = fexp2(Mm[i * 16 + r] - mf);
    lf += Ll[i * 16 + r] * sc;
    const float* p = OmF + i * 1088 + r * 68 + 2 * cp;
    o0 += p[0] * sc;
    o1 += p[1] * sc;
  }
  const float inv = 1.0f / lf;
  float2 o;
  o.x = o0 * inv;
  o.y = o1 * inv;
  *(float2*)(out + (size_t)(b * 2048 + q0 + r) * 64 + 2 * cp) = o;
}

// ---------------- kernel 3: causal flash attention, paired q-tiles ----------------
// Block = 512 threads = 8 waves, handles the complementary pair (qt, 127-qt):
// total k-blocks nbA+nbB = 33-34 for EVERY block -> uniform block work, no
// idle waves, no drain tail. Each wave runs two sequential flash loops
// (separate named states), then two LDS combine phases reusing the 35.8 KB.
__global__ __launch_bounds__(512) void attn_kernel(const _Float16* __restrict__ Qh,
                                                   const _Float16* __restrict__ Kh,
                                                   const _Float16* __restrict__ Vt,
                                                   float* __restrict__ out) {
  __shared__ __align__(16) char shraw[35840];

  const int tid = threadIdx.x;
  const int lane = tid & 63;
  const int wv = tid >> 6;       // 0..7
  const int g = lane >> 4;
  const int c = lane & 15;
  const int pr = blockIdx.x & 63;   // pair index 0..63
  const int b = blockIdx.x >> 6;
  const int q0A = pr * 16;              // small tile
  const int q0B = (127 - pr) * 16;      // large tile

  const _Float16* Qb = Qh + (size_t)b * 2048 * 64;
  const _Float16* Kb = Kh + (size_t)b * 2048 * 64;
  const _Float16* Vb = Vt + (size_t)b * 64 * 2048;

  const f32x4 zero = {0.f, 0.f, 0.f, 0.f};
  f32x4 accA[4], accB[4];
#pragma unroll
  for (int t = 0; t < 4; ++t) { accA[t] = zero; accB[t] = zero; }
  float mA = -3.0e38f, lA = 0.f;
  float mB = -3.0e38f, lB = 0.f;

  flash_tile(q0A, wv, g, c, Qb, Kb, Vb, accA, mA, lA);
  flash_tile(q0B, wv, g, c, Qb, Kb, Vb, accB, mB, lB);

  combine_tile(shraw, tid, wv, g, c, b, q0A, accA, mA, lA, out);
  __syncthreads();  // A's Om reads done before B overwrites
  combine_tile(shraw, tid, wv, g, c, b, q0B, accB, mB, lB, out);
}

extern "C" void kernel_launch(void* const* d_in, const int* in_sizes, int n_in,
                              void* d_out, int out_size, void* d_ws, size_t ws_size,
                              hipStream_t stream) {
  const float* x  = (const float*)d_in[0];
  const float* Wq = (const float*)d_in[1];
  const float* Wk = (const float*)d_in[2];
  const float* Wv = (const float*)d_in[3];
  char* ws = (char*)d_ws;
  _Float16* Wt = (_Float16*)(ws);                // 192*1024*2      = 393216 B
  _Float16* Qh = (_Float16*)(ws + 393216);       // 16384*64*2      = 2097152 B
  _Float16* Kh = (_Float16*)(ws + 2490368);      // 16384*64*2
  _Float16* Vt = (_Float16*)(ws + 4587520);      // 8*64*2048*2
  float* out = (float*)d_out;

  wt_kernel<<<dim3(768), dim3(256), 0, stream>>>(Wq, Wk, Wv, Wt);
  proj_kernel<<<dim3(512), dim3(256), 0, stream>>>(x, Wt, Qh, Kh, Vt);
  attn_kernel<<<dim3(512), dim3(512), 0, stream>>>(Qh, Kh, Vt, out);
}